// Round 6
// baseline (1023.554 us; speedup 1.0000x reference)
//
#include <hip/hip_runtime.h>
#include <math.h>

#define V_N 8192
#define D_F 128
#define E_N 262144
#define K_N 512
#define DMAXF 0.5f
#define EPSW 1e-8f
#define EPSL 1e-5f
#define MAX_SE 16384
#define NZ_SYRK 24
#define LDS68 68

// ---------- transpose pmat (KxV)->PT (VxK) 64x64 float4 tiles, + Lw1 <- T copy ----------
__global__ __launch_bounds__(256) void k_tr(const float* __restrict__ P, float* __restrict__ PT,
                                            const float* __restrict__ T, float* __restrict__ Lw1) {
  int b = blockIdx.x, tid = threadIdx.x;
  if (b < 1024) {
    __shared__ float tl[64][65];
    int v0 = (b & 127) * 64, k0 = (b >> 7) * 64;
    int c4 = tid & 15, rq = tid >> 4;
#pragma unroll
    for (int rr = 0; rr < 4; ++rr) {
      int r = rq + 16 * rr;
      float4 f = *(const float4*)&P[(size_t)(k0 + r) * V_N + v0 + c4 * 4];
      tl[r][c4 * 4 + 0] = f.x; tl[r][c4 * 4 + 1] = f.y;
      tl[r][c4 * 4 + 2] = f.z; tl[r][c4 * 4 + 3] = f.w;
    }
    __syncthreads();
#pragma unroll
    for (int rr = 0; rr < 4; ++rr) {
      int r = rq + 16 * rr;   // v-local row
      float4 f;
      f.x = tl[c4 * 4 + 0][r]; f.y = tl[c4 * 4 + 1][r];
      f.z = tl[c4 * 4 + 2][r]; f.w = tl[c4 * 4 + 3][r];
      *(float4*)&PT[(size_t)(v0 + r) * K_N + k0 + c4 * 4] = f;
    }
  } else {
    int idx = (b - 1024) * 256 + tid;
    ((float4*)Lw1)[idx] = ((const float4*)T)[idx];
  }
}

// ---------- per-edge distance (8 lanes/edge), strong-edge dedup + compaction ----------
__global__ __launch_bounds__(256) void k_edge(const float* __restrict__ X, const int* __restrict__ ei,
                                              int* __restrict__ cnt, int* __restrict__ si,
                                              int* __restrict__ sj, float* __restrict__ sw,
                                              unsigned* __restrict__ htab) {
  int t = blockIdx.x * 256 + threadIdx.x;
  int e = t >> 3, lane = t & 7;
  int i = ei[e], j = ei[E_N + e];
  const float4* xi = (const float4*)(X + (size_t)i * D_F);
  const float4* xj = (const float4*)(X + (size_t)j * D_F);
  float4 A0 = xi[lane * 4 + 0], A1 = xi[lane * 4 + 1], A2 = xi[lane * 4 + 2], A3 = xi[lane * 4 + 3];
  float4 B0 = xj[lane * 4 + 0], B1 = xj[lane * 4 + 1], B2 = xj[lane * 4 + 2], B3 = xj[lane * 4 + 3];
  float d = 0.f, dx;
  dx = A0.x - B0.x; d += dx * dx; dx = A0.y - B0.y; d += dx * dx;
  dx = A0.z - B0.z; d += dx * dx; dx = A0.w - B0.w; d += dx * dx;
  dx = A1.x - B1.x; d += dx * dx; dx = A1.y - B1.y; d += dx * dx;
  dx = A1.z - B1.z; d += dx * dx; dx = A1.w - B1.w; d += dx * dx;
  dx = A2.x - B2.x; d += dx * dx; dx = A2.y - B2.y; d += dx * dx;
  dx = A2.z - B2.z; d += dx * dx; dx = A2.w - B2.w; d += dx * dx;
  dx = A3.x - B3.x; d += dx * dx; dx = A3.y - B3.y; d += dx * dx;
  dx = A3.z - B3.z; d += dx * dx; dx = A3.w - B3.w; d += dx * dx;
  d += __shfl_xor(d, 1);
  d += __shfl_xor(d, 2);
  d += __shfl_xor(d, 4);
  if (lane == 0 && d <= DMAXF) {
    float w = expf(-d);
    unsigned a = (unsigned)min(i, j), bb = (unsigned)max(i, j);
    unsigned key = a * 8192u + bb;         // key==0 impossible (a<b)
    unsigned h = (key * 2654435761u) >> 16;
    bool isnew = false;
    for (int probe = 0; probe < 65536; ++probe) {
      unsigned slot = (h + (unsigned)probe) & 65535u;
      unsigned prev = atomicCAS(&htab[slot], 0u, key);
      if (prev == 0u) { isnew = true; break; }
      if (prev == key) break;              // duplicate pair -> reference counts it once
    }
    if (isnew) {
      int p = atomicAdd(cnt, 1);
      if (p < MAX_SE) { si[p] = i; sj[p] = j; sw[p] = w; }
    }
  }
}

// ---------- La(lower) += Q^T Q + eps*I, Q rows = sqrt(w)*(PT[i]-PT[j]); fused trace epilogue ----------
__global__ __launch_bounds__(256) void k_syrk(const int* __restrict__ cnt, const int* __restrict__ si,
                                              const int* __restrict__ sj, const float* __restrict__ sw,
                                              const float* __restrict__ PT, float* __restrict__ La,
                                              const float* __restrict__ T, float* __restrict__ tr) {
  int p = blockIdx.x, bj = 0;
  while (p >= 8 - bj) { p -= 8 - bj; ++bj; }
  int bi = bj + p;
  int r0g = bi * 64, c0g = bj * 64;
  int m = min(*cnt, MAX_SE);
  int chunk = (m + NZ_SYRK - 1) / NZ_SYRK;
  int e0 = blockIdx.y * chunk;
  int e1 = min(m, e0 + chunk);

  __shared__ float As[16][68];
  __shared__ float Bs[16][68];
  int tid = threadIdx.x;
  int le = tid >> 4, f = tid & 15;
  int r0 = (tid >> 4) * 4, c0 = (tid & 15) * 4;
  float acc[4][4];
#pragma unroll
  for (int i = 0; i < 4; ++i)
#pragma unroll
    for (int j = 0; j < 4; ++j) acc[i][j] = 0.f;

  float w_ = 0.f;
  float4 ai = make_float4(0.f, 0.f, 0.f, 0.f), aj = ai, ci = ai, cj = ai;
  {
    int e = e0 + le;
    if (e < e1) {
      int i = si[e], j = sj[e];
      w_ = sw[e];
      const float* pi = &PT[(size_t)i * K_N];
      const float* pj = &PT[(size_t)j * K_N];
      ai = *(const float4*)(pi + r0g + f * 4);
      aj = *(const float4*)(pj + r0g + f * 4);
      if (bi != bj) {
        ci = *(const float4*)(pi + c0g + f * 4);
        cj = *(const float4*)(pj + c0g + f * 4);
      }
    }
  }

  for (int es = e0; es < e1; es += 16) {
    float sq = sqrtf(w_);
    float4 qa, qb;
    qa.x = sq * (ai.x - aj.x); qa.y = sq * (ai.y - aj.y);
    qa.z = sq * (ai.z - aj.z); qa.w = sq * (ai.w - aj.w);
    if (bi != bj) {
      qb.x = sq * (ci.x - cj.x); qb.y = sq * (ci.y - cj.y);
      qb.z = sq * (ci.z - cj.z); qb.w = sq * (ci.w - cj.w);
    } else {
      qb = qa;
    }
    __syncthreads();
    *(float4*)&As[le][f * 4] = qa;
    *(float4*)&Bs[le][f * 4] = qb;
    __syncthreads();

    {
      int e = es + 16 + le;
      w_ = 0.f;
      if (e < e1) {
        int i = si[e], j = sj[e];
        w_ = sw[e];
        const float* pi = &PT[(size_t)i * K_N];
        const float* pj = &PT[(size_t)j * K_N];
        ai = *(const float4*)(pi + r0g + f * 4);
        aj = *(const float4*)(pj + r0g + f * 4);
        if (bi != bj) {
          ci = *(const float4*)(pi + c0g + f * 4);
          cj = *(const float4*)(pj + c0g + f * 4);
        }
      }
    }

#pragma unroll
    for (int k = 0; k < 16; ++k) {
      float4 av = *(const float4*)&As[k][r0];
      float4 bv = *(const float4*)&Bs[k][c0];
      acc[0][0] += av.x * bv.x; acc[0][1] += av.x * bv.y; acc[0][2] += av.x * bv.z; acc[0][3] += av.x * bv.w;
      acc[1][0] += av.y * bv.x; acc[1][1] += av.y * bv.y; acc[1][2] += av.y * bv.z; acc[1][3] += av.y * bv.w;
      acc[2][0] += av.z * bv.x; acc[2][1] += av.z * bv.y; acc[2][2] += av.z * bv.z; acc[2][3] += av.z * bv.w;
      acc[3][0] += av.w * bv.x; acc[3][1] += av.w * bv.y; acc[3][2] += av.w * bv.z; acc[3][3] += av.w * bv.w;
    }
  }

  bool addeps = (blockIdx.y == 0) && (bi == bj);
  float tdot = 0.f;
#pragma unroll
  for (int i = 0; i < 4; ++i)
#pragma unroll
    for (int j = 0; j < 4; ++j) {
      float v = acc[i][j];
      int rg = r0g + r0 + i, cg = c0g + c0 + j;
      if (addeps && rg == cg) v += EPSL;
      atomicAdd(&La[(size_t)rg * K_N + cg], v);
      float sc = (bi != bj) ? 2.f : (rg == cg ? 1.f : (rg > cg ? 2.f : 0.f));
      if (sc != 0.f) tdot += sc * v * T[(size_t)rg * K_N + cg];
    }
  tdot += __shfl_down(tdot, 32); tdot += __shfl_down(tdot, 16); tdot += __shfl_down(tdot, 8);
  tdot += __shfl_down(tdot, 4);  tdot += __shfl_down(tdot, 2);  tdot += __shfl_down(tdot, 1);
  if ((tid & 63) == 0) atomicAdd(tr, tdot);
}

// ---------- persistent fused 2-matrix Cholesky ----------
__device__ __forceinline__ void gbar(unsigned* c_, unsigned& ep) {
  ep += 8;
  __syncthreads();
  __threadfence();
  if (threadIdx.x == 0) {
    __hip_atomic_fetch_add(c_, 1u, __ATOMIC_RELEASE, __HIP_MEMORY_SCOPE_AGENT);
    while (__hip_atomic_load(c_, __ATOMIC_ACQUIRE, __HIP_MEMORY_SCOPE_AGENT) < ep)
      __builtin_amdgcn_s_sleep(2);
  }
  __syncthreads();
  __threadfence();
}

// in-register 64x64 Cholesky by wave 0; src: LDS (smF) or global diag block
__device__ __forceinline__ void factor64(float* A, int j0, const float* smFsrc,
                                         float* ldout, int tid) {
  if (tid >= 64) return;
  int r = tid;
  float a[64];
  if (smFsrc) {
#pragma unroll
    for (int q = 0; q < 16; ++q) {
      float4 f = *(const float4*)&smFsrc[r * LDS68 + q * 4];
      a[q * 4 + 0] = f.x; a[q * 4 + 1] = f.y; a[q * 4 + 2] = f.z; a[q * 4 + 3] = f.w;
    }
  } else {
#pragma unroll
    for (int q = 0; q < 16; ++q) {
      float4 f = *(const float4*)&A[(size_t)(j0 + r) * K_N + j0 + q * 4];
      a[q * 4 + 0] = f.x; a[q * 4 + 1] = f.y; a[q * 4 + 2] = f.z; a[q * 4 + 3] = f.w;
    }
  }
  float ls = 0.f;
#pragma unroll
  for (int c = 0; c < 64; ++c) {
    float dc = __shfl(a[c], c);          // fully-updated diagonal = L_cc^2
    ls += logf(dc);
    float rs = rsqrtf(dc);
    a[c] *= rs;
#pragma unroll
    for (int k = c + 1; k < 64; ++k)
      a[k] -= a[c] * __shfl(a[c], k);
  }
#pragma unroll
  for (int q = 0; q < 16; ++q) {
    float4 f;
    f.x = a[q * 4 + 0]; f.y = a[q * 4 + 1]; f.z = a[q * 4 + 2]; f.w = a[q * 4 + 3];
    *(float4*)&A[(size_t)(j0 + r) * K_N + j0 + q * 4] = f;
  }
  if (r == 0) *ldout = ls;
}

// rank-64 trailing-update of one 64x64 tile; optionally stage result to smF (no global write)
__device__ __forceinline__ void upd_tile(float* A, int sbase, int q, int nt2, bool toSmF,
                                         float* As_, float* Bs_, float* smF, int tid) {
  int lbj = 0;
  while (q >= nt2 - lbj) { q -= nt2 - lbj; ++lbj; }
  int lbi = lbj + q;
  int r0g = (sbase + lbi) * 64, c0g = (sbase + lbj) * 64, k0g = (sbase - 1) * 64;
  __syncthreads();                       // protect LDS from previous phase/tile
  for (int i = tid; i < 1024; i += 512) {
    int r = i >> 4, kq = (i & 15) << 2;
    float4 f = *(const float4*)&A[(size_t)(r0g + r) * K_N + k0g + kq];
    As_[(kq + 0) * LDS68 + r] = f.x; As_[(kq + 1) * LDS68 + r] = f.y;
    As_[(kq + 2) * LDS68 + r] = f.z; As_[(kq + 3) * LDS68 + r] = f.w;
    float4 g = *(const float4*)&A[(size_t)(c0g + r) * K_N + k0g + kq];
    Bs_[(kq + 0) * LDS68 + r] = g.x; Bs_[(kq + 1) * LDS68 + r] = g.y;
    Bs_[(kq + 2) * LDS68 + r] = g.z; Bs_[(kq + 3) * LDS68 + r] = g.w;
  }
  __syncthreads();
  int r0 = (tid >> 4) * 2, c0 = (tid & 15) * 4;
  float acc[2][4];
#pragma unroll
  for (int i = 0; i < 2; ++i)
#pragma unroll
    for (int j = 0; j < 4; ++j) acc[i][j] = 0.f;
#pragma unroll 8
  for (int k = 0; k < 64; ++k) {
    float a0 = As_[k * LDS68 + r0], a1 = As_[k * LDS68 + r0 + 1];
    float4 bv = *(const float4*)&Bs_[k * LDS68 + c0];
    acc[0][0] += a0 * bv.x; acc[0][1] += a0 * bv.y; acc[0][2] += a0 * bv.z; acc[0][3] += a0 * bv.w;
    acc[1][0] += a1 * bv.x; acc[1][1] += a1 * bv.y; acc[1][2] += a1 * bv.z; acc[1][3] += a1 * bv.w;
  }
  if (toSmF) {
#pragma unroll
    for (int i = 0; i < 2; ++i) {
      const float* cp = &A[(size_t)(r0g + r0 + i) * K_N + c0g + c0];
      float4 co = *(const float4*)cp;
      smF[(r0 + i) * LDS68 + c0 + 0] = co.x - acc[i][0];
      smF[(r0 + i) * LDS68 + c0 + 1] = co.y - acc[i][1];
      smF[(r0 + i) * LDS68 + c0 + 2] = co.z - acc[i][2];
      smF[(r0 + i) * LDS68 + c0 + 3] = co.w - acc[i][3];
    }
  } else {
#pragma unroll
    for (int i = 0; i < 2; ++i) {
      float* cp = &A[(size_t)(r0g + r0 + i) * K_N + c0g + c0];
      cp[0] -= acc[i][0]; cp[1] -= acc[i][1]; cp[2] -= acc[i][2]; cp[3] -= acc[i][3];
    }
  }
}

__global__ __launch_bounds__(512, 1) void k_chol2(float* La, float* Lw1, float* __restrict__ ld,
                                                  unsigned* __restrict__ ctr) {
  int mat = blockIdx.x >> 3;
  int b = blockIdx.x & 7;
  float* A = mat ? Lw1 : La;
  unsigned* myctr = ctr + mat * 16;      // 64B apart
  int tid = threadIdx.x;
  __shared__ float sh[3 * 64 * LDS68 + 64];
  float* As_ = sh;
  float* Bs_ = sh + 64 * LDS68;
  float* smF = sh + 2 * 64 * LDS68;
  float* rin = sh + 3 * 64 * LDS68;
  unsigned ep = 0;
  __threadfence();                       // invalidate L1 vs prior kernels' writes

  for (int s = 0; s < 8; ++s) {
    const int j0 = s * 64;
    int rel = (b - s) & 7;
    if (s == 0) {
      if (b == 0) factor64(A, 0, nullptr, &ld[mat * 8], tid);
    } else {
      int nt2 = 8 - s;
      int cntT = nt2 * (nt2 + 1) / 2;
      if (rel == 0) {
        upd_tile(A, s, 0, nt2, true, As_, Bs_, smF, tid);   // diag tile -> smF
        __syncthreads();
        factor64(A, j0, smF, &ld[mat * 8 + s], tid);
      } else {
        for (int q = rel; q < cntT; q += 7)
          upd_tile(A, s, q, nt2, false, As_, Bs_, smF, tid);
      }
    }
    gbar(myctr, ep);

    if (b < 7 - s) {
      // stage smT[c][k] = L[j0+k][j0+c] (lower triangle transposed) into As_
      __syncthreads();
      for (int idx = tid; idx < 4096; idx += 512) {
        int k = idx >> 6, c = idx & 63;
        As_[c * LDS68 + k] = A[(size_t)(j0 + k) * K_N + j0 + c];
      }
      __syncthreads();
      if (tid < 64) rin[tid] = 1.0f / As_[tid * LDS68 + tid];
      __syncthreads();
      if (tid < 64) {
        int row = (s + 1 + b) * 64 + tid;
        float x[64];
#pragma unroll
        for (int q = 0; q < 16; ++q) {
          float4 f = *(const float4*)&A[(size_t)row * K_N + j0 + q * 4];
          x[q * 4 + 0] = f.x; x[q * 4 + 1] = f.y; x[q * 4 + 2] = f.z; x[q * 4 + 3] = f.w;
        }
#pragma unroll
        for (int c = 0; c < 64; ++c) {
          float xc = x[c] * rin[c];
          x[c] = xc;
          int kk = c + 1;
#pragma unroll
          for (; kk < 64 && (kk & 3); ++kk) x[kk] -= xc * As_[c * LDS68 + kk];
#pragma unroll
          for (; kk < 64; kk += 4) {
            float4 f = *(const float4*)&As_[c * LDS68 + kk];
            x[kk + 0] -= xc * f.x; x[kk + 1] -= xc * f.y;
            x[kk + 2] -= xc * f.z; x[kk + 3] -= xc * f.w;
          }
        }
#pragma unroll
        for (int q = 0; q < 16; ++q) {
          float4 f;
          f.x = x[q * 4 + 0]; f.y = x[q * 4 + 1]; f.z = x[q * 4 + 2]; f.w = x[q * 4 + 3];
          *(float4*)&A[(size_t)row * K_N + j0 + q * 4] = f;
        }
      }
    }
    gbar(myctr, ep);
  }
}

// ---------- combine ----------
__global__ void k_combine(const float* __restrict__ ld, const float* __restrict__ tr, float* __restrict__ out) {
  float l0 = 0.f, l1 = 0.f;
#pragma unroll
  for (int s = 0; s < 8; ++s) { l0 += ld[s]; l1 += ld[8 + s]; }
  out[0] = -l0 - l1 - (float)K_N + tr[0];
}

extern "C" void kernel_launch(void* const* d_in, const int* in_sizes, int n_in,
                              void* d_out, int out_size, void* d_ws, size_t ws_size,
                              hipStream_t stream) {
  const float* X  = (const float*)d_in[0];   // inputs  [V,128]
  const float* T  = (const float*)d_in[1];   // targets [K,K]
  const int*   ei = (const int*)d_in[2];     // edge_index [2,E]
  const float* P  = (const float*)d_in[3];   // pmat [K,V]
  float* out = (float*)d_out;
  char* ws = (char*)d_ws;

  // workspace layout (bytes); [0, 1314816) is one contiguous zero-memset region
  int*      cnt  = (int*)(ws + 0);
  float*    tr   = (float*)(ws + 16);
  float*    ld   = (float*)(ws + 32);            // 16 floats
  unsigned* bar  = (unsigned*)(ws + 128);        // 2 counters, 64B apart
  unsigned* htab = (unsigned*)(ws + 4096);       // 65536 u32 (256 KB) -> 266240
  float*    La   = (float*)(ws + 266240);        // K*K (1 MB) -> 1314816  (zeroed; lower filled)
  float*    Lw1  = (float*)(ws + 1314816);       // K*K (1 MB) -> 2363392  (copied from T in k_tr)
  int*      si   = (int*)(ws + 2363392);         // 16384 ints -> 2428928
  int*      sj   = (int*)(ws + 2428928);         // 16384 ints -> 2494464
  float*    sw   = (float*)(ws + 2494464);       // 16384 floats -> 2560000
  float*    PT   = (float*)(ws + 2560000);       // V*K floats (16 MB) -> 19337216

  hipMemsetAsync(ws, 0, 1314816, stream);        // cnt, tr, ld, bar, htab, La

  k_tr<<<1280, 256, 0, stream>>>(P, PT, T, Lw1);
  k_edge<<<E_N / 32, 256, 0, stream>>>(X, ei, cnt, si, sj, sw, htab);
  k_syrk<<<dim3(36, NZ_SYRK), 256, 0, stream>>>(cnt, si, sj, sw, PT, La, T, tr);
  k_chol2<<<16, 512, 0, stream>>>(La, Lw1, ld, bar);
  k_combine<<<1, 1, 0, stream>>>(ld, tr, out);
}

// Round 7
// 965.864 us; speedup vs baseline: 1.0597x; 1.0597x over previous
//
#include <hip/hip_runtime.h>
#include <math.h>

#define V_N 8192
#define D_F 128
#define E_N 262144
#define K_N 512
#define DMAXF 0.5f
#define EPSW 1e-8f
#define EPSL 1e-5f
#define MAX_SE 16384
#define NZ_SYRK 24
#define L68 68

// ---------- transpose pmat (KxV)->PT (VxK) 64x64 float4 tiles, + Lw1 <- T copy ----------
__global__ __launch_bounds__(256) void k_tr(const float* __restrict__ P, float* __restrict__ PT,
                                            const float* __restrict__ T, float* __restrict__ Lw1) {
  int b = blockIdx.x, tid = threadIdx.x;
  if (b < 1024) {
    __shared__ float tl[64][65];
    int v0 = (b & 127) * 64, k0 = (b >> 7) * 64;
    int c4 = tid & 15, rq = tid >> 4;
#pragma unroll
    for (int rr = 0; rr < 4; ++rr) {
      int r = rq + 16 * rr;
      float4 f = *(const float4*)&P[(size_t)(k0 + r) * V_N + v0 + c4 * 4];
      tl[r][c4 * 4 + 0] = f.x; tl[r][c4 * 4 + 1] = f.y;
      tl[r][c4 * 4 + 2] = f.z; tl[r][c4 * 4 + 3] = f.w;
    }
    __syncthreads();
#pragma unroll
    for (int rr = 0; rr < 4; ++rr) {
      int r = rq + 16 * rr;   // v-local row
      float4 f;
      f.x = tl[c4 * 4 + 0][r]; f.y = tl[c4 * 4 + 1][r];
      f.z = tl[c4 * 4 + 2][r]; f.w = tl[c4 * 4 + 3][r];
      *(float4*)&PT[(size_t)(v0 + r) * K_N + k0 + c4 * 4] = f;
    }
  } else {
    int idx = (b - 1024) * 256 + tid;
    ((float4*)Lw1)[idx] = ((const float4*)T)[idx];
  }
}

// ---------- per-edge distance (8 lanes/edge), strong-edge dedup + compaction ----------
__global__ __launch_bounds__(256) void k_edge(const float* __restrict__ X, const int* __restrict__ ei,
                                              int* __restrict__ cnt, int* __restrict__ si,
                                              int* __restrict__ sj, float* __restrict__ sw,
                                              unsigned* __restrict__ htab) {
  int t = blockIdx.x * 256 + threadIdx.x;
  int e = t >> 3, lane = t & 7;
  int i = ei[e], j = ei[E_N + e];
  const float4* xi = (const float4*)(X + (size_t)i * D_F);
  const float4* xj = (const float4*)(X + (size_t)j * D_F);
  float4 A0 = xi[lane * 4 + 0], A1 = xi[lane * 4 + 1], A2 = xi[lane * 4 + 2], A3 = xi[lane * 4 + 3];
  float4 B0 = xj[lane * 4 + 0], B1 = xj[lane * 4 + 1], B2 = xj[lane * 4 + 2], B3 = xj[lane * 4 + 3];
  float d = 0.f, dx;
  dx = A0.x - B0.x; d += dx * dx; dx = A0.y - B0.y; d += dx * dx;
  dx = A0.z - B0.z; d += dx * dx; dx = A0.w - B0.w; d += dx * dx;
  dx = A1.x - B1.x; d += dx * dx; dx = A1.y - B1.y; d += dx * dx;
  dx = A1.z - B1.z; d += dx * dx; dx = A1.w - B1.w; d += dx * dx;
  dx = A2.x - B2.x; d += dx * dx; dx = A2.y - B2.y; d += dx * dx;
  dx = A2.z - B2.z; d += dx * dx; dx = A2.w - B2.w; d += dx * dx;
  dx = A3.x - B3.x; d += dx * dx; dx = A3.y - B3.y; d += dx * dx;
  dx = A3.z - B3.z; d += dx * dx; dx = A3.w - B3.w; d += dx * dx;
  d += __shfl_xor(d, 1);
  d += __shfl_xor(d, 2);
  d += __shfl_xor(d, 4);
  if (lane == 0 && d <= DMAXF) {
    float w = expf(-d);
    unsigned a = (unsigned)min(i, j), bb = (unsigned)max(i, j);
    unsigned key = a * 8192u + bb;         // key==0 impossible (a<b)
    unsigned h = (key * 2654435761u) >> 16;
    bool isnew = false;
    for (int probe = 0; probe < 65536; ++probe) {
      unsigned slot = (h + (unsigned)probe) & 65535u;
      unsigned prev = atomicCAS(&htab[slot], 0u, key);
      if (prev == 0u) { isnew = true; break; }
      if (prev == key) break;              // duplicate pair -> reference counts it once
    }
    if (isnew) {
      int p = atomicAdd(cnt, 1);
      if (p < MAX_SE) { si[p] = i; sj[p] = j; sw[p] = w; }
    }
  }
}

// ---------- La(lower) += Q^T Q + eps*I, Q rows = sqrt(w)*(PT[i]-PT[j]); fused trace epilogue ----------
__global__ __launch_bounds__(256) void k_syrk(const int* __restrict__ cnt, const int* __restrict__ si,
                                              const int* __restrict__ sj, const float* __restrict__ sw,
                                              const float* __restrict__ PT, float* __restrict__ La,
                                              const float* __restrict__ T, float* __restrict__ tr) {
  int p = blockIdx.x, bj = 0;
  while (p >= 8 - bj) { p -= 8 - bj; ++bj; }
  int bi = bj + p;
  int r0g = bi * 64, c0g = bj * 64;
  int m = min(*cnt, MAX_SE);
  int chunk = (m + NZ_SYRK - 1) / NZ_SYRK;
  int e0 = blockIdx.y * chunk;
  int e1 = min(m, e0 + chunk);

  __shared__ float As[16][68];
  __shared__ float Bs[16][68];
  int tid = threadIdx.x;
  int le = tid >> 4, f = tid & 15;
  int r0 = (tid >> 4) * 4, c0 = (tid & 15) * 4;
  float acc[4][4];
#pragma unroll
  for (int i = 0; i < 4; ++i)
#pragma unroll
    for (int j = 0; j < 4; ++j) acc[i][j] = 0.f;

  float w_ = 0.f;
  float4 ai = make_float4(0.f, 0.f, 0.f, 0.f), aj = ai, ci = ai, cj = ai;
  {
    int e = e0 + le;
    if (e < e1) {
      int i = si[e], j = sj[e];
      w_ = sw[e];
      const float* pi = &PT[(size_t)i * K_N];
      const float* pj = &PT[(size_t)j * K_N];
      ai = *(const float4*)(pi + r0g + f * 4);
      aj = *(const float4*)(pj + r0g + f * 4);
      if (bi != bj) {
        ci = *(const float4*)(pi + c0g + f * 4);
        cj = *(const float4*)(pj + c0g + f * 4);
      }
    }
  }

  for (int es = e0; es < e1; es += 16) {
    float sq = sqrtf(w_);
    float4 qa, qb;
    qa.x = sq * (ai.x - aj.x); qa.y = sq * (ai.y - aj.y);
    qa.z = sq * (ai.z - aj.z); qa.w = sq * (ai.w - aj.w);
    if (bi != bj) {
      qb.x = sq * (ci.x - cj.x); qb.y = sq * (ci.y - cj.y);
      qb.z = sq * (ci.z - cj.z); qb.w = sq * (ci.w - cj.w);
    } else {
      qb = qa;
    }
    __syncthreads();
    *(float4*)&As[le][f * 4] = qa;
    *(float4*)&Bs[le][f * 4] = qb;
    __syncthreads();

    {
      int e = es + 16 + le;
      w_ = 0.f;
      if (e < e1) {
        int i = si[e], j = sj[e];
        w_ = sw[e];
        const float* pi = &PT[(size_t)i * K_N];
        const float* pj = &PT[(size_t)j * K_N];
        ai = *(const float4*)(pi + r0g + f * 4);
        aj = *(const float4*)(pj + r0g + f * 4);
        if (bi != bj) {
          ci = *(const float4*)(pi + c0g + f * 4);
          cj = *(const float4*)(pj + c0g + f * 4);
        }
      }
    }

#pragma unroll
    for (int k = 0; k < 16; ++k) {
      float4 av = *(const float4*)&As[k][r0];
      float4 bv = *(const float4*)&Bs[k][c0];
      acc[0][0] += av.x * bv.x; acc[0][1] += av.x * bv.y; acc[0][2] += av.x * bv.z; acc[0][3] += av.x * bv.w;
      acc[1][0] += av.y * bv.x; acc[1][1] += av.y * bv.y; acc[1][2] += av.y * bv.z; acc[1][3] += av.y * bv.w;
      acc[2][0] += av.z * bv.x; acc[2][1] += av.z * bv.y; acc[2][2] += av.z * bv.z; acc[2][3] += av.z * bv.w;
      acc[3][0] += av.w * bv.x; acc[3][1] += av.w * bv.y; acc[3][2] += av.w * bv.z; acc[3][3] += av.w * bv.w;
    }
  }

  bool addeps = (blockIdx.y == 0) && (bi == bj);
  float tdot = 0.f;
#pragma unroll
  for (int i = 0; i < 4; ++i)
#pragma unroll
    for (int j = 0; j < 4; ++j) {
      float v = acc[i][j];
      int rg = r0g + r0 + i, cg = c0g + c0 + j;
      if (addeps && rg == cg) v += EPSL;
      atomicAdd(&La[(size_t)rg * K_N + cg], v);
      float sc = (bi != bj) ? 2.f : (rg == cg ? 1.f : (rg > cg ? 2.f : 0.f));
      if (sc != 0.f) tdot += sc * v * T[(size_t)rg * K_N + cg];
    }
  tdot += __shfl_down(tdot, 32); tdot += __shfl_down(tdot, 16); tdot += __shfl_down(tdot, 8);
  tdot += __shfl_down(tdot, 4);  tdot += __shfl_down(tdot, 2);  tdot += __shfl_down(tdot, 1);
  if ((tid & 63) == 0) atomicAdd(tr, tdot);
}

// ---------- in-register 64x64 Cholesky factor (wave 0). smF row-major stride L68.
// Writes L rows to A diag tile (j0,j0), keeps row in a[], logdet sum -> *ldout (lane 0 only).
__device__ __forceinline__ void factor64(const float* smF, float* A, int j0, float* ldout,
                                         float a[64], int lane) {
#pragma unroll
  for (int q = 0; q < 16; ++q) {
    float4 f = *(const float4*)&smF[lane * L68 + q * 4];
    a[q * 4 + 0] = f.x; a[q * 4 + 1] = f.y; a[q * 4 + 2] = f.z; a[q * 4 + 3] = f.w;
  }
  float ls = 0.f;
#pragma unroll
  for (int c = 0; c < 64; ++c) {
    float dc = __shfl(a[c], c);          // fully-updated diagonal = L_cc^2
    ls += logf(dc);
    float rs = rsqrtf(dc);
    a[c] *= rs;
#pragma unroll
    for (int k = c + 1; k < 64; ++k)
      a[k] -= a[c] * __shfl(a[c], k);
  }
#pragma unroll
  for (int q = 0; q < 16; ++q) {
    float4 f;
    f.x = a[q * 4 + 0]; f.y = a[q * 4 + 1]; f.z = a[q * 4 + 2]; f.w = a[q * 4 + 3];
    *(float4*)&A[(size_t)(j0 + lane) * K_N + j0 + q * 4] = f;
  }
  if (lane == 0) *ldout = ls;
}

// ---------- in-register inv(L): lane c computes column c of inv(L); ib[c*64+k] = invL[k][c]
__device__ __forceinline__ void invert64(const float a[64], float* __restrict__ ib, int lane) {
  float y[64];
#pragma unroll
  for (int k = 0; k < 64; ++k) {
    float t = (k == lane) ? 1.f : 0.f;
#pragma unroll
    for (int mm = 0; mm < k; ++mm)
      t -= __shfl(a[mm], k) * y[mm];     // L[k][mm]
    y[k] = t / __shfl(a[k], k);          // / L[k][k]
  }
#pragma unroll
  for (int q = 0; q < 16; ++q) {
    float4 f;
    f.x = y[q * 4 + 0]; f.y = y[q * 4 + 1]; f.z = y[q * 4 + 2]; f.w = y[q * 4 + 3];
    *(float4*)&ib[lane * 64 + q * 4] = f;
  }
}

// ---------- chol step 0: factor tile (0,0) of both matrices + invert ----------
__global__ __launch_bounds__(512, 1) void k_diag0(float* La, float* Lw1, float* __restrict__ ibuf,
                                                  float* __restrict__ ld) {
  int m = blockIdx.x;
  float* A = m ? Lw1 : La;
  float* ib = ibuf + m * 4096;
  int tid = threadIdx.x;
  __shared__ float smF[64 * L68];
  for (int idx = tid; idx < 1024; idx += 512) {
    int r = idx >> 4, cq = (idx & 15) << 2;
    *(float4*)&smF[r * L68 + cq] = *(const float4*)&A[(size_t)r * K_N + cq];
  }
  __syncthreads();
  if (tid < 64) {
    float a[64];
    factor64(smF, A, 0, &ld[m * 8], a, tid);
    invert64(a, ib, tid);
  }
}

// ---------- chol step s (0..6): left-looking update of column s+..., TRSM-as-GEMM with invL,
// block 0 additionally updates+factors diag tile (s+1,s+1) and produces next invL ----------
__global__ __launch_bounds__(512, 1) void k_step(float* La, float* Lw1, float* __restrict__ ibuf,
                                                 float* __restrict__ ld, int s) {
  int m = blockIdx.y;
  float* A = m ? Lw1 : La;
  float* ib = ibuf + m * 4096;
  int tid = threadIdx.x;
  int i = s + 1 + blockIdx.x;            // row-block handled by this block
  int r0 = (tid >> 4) * 2, c0 = (tid & 15) * 4;
  __shared__ float As_[64 * L68];
  __shared__ float Bs_[64 * L68];
  __shared__ float CT_[64 * L68];        // C transposed: CT_[k][r]
  __shared__ float B2_[64 * L68];        // B2_[k][c] = invL[c][k]

  // stage invL (producer = previous dispatch)
  for (int idx = tid; idx < 1024; idx += 512) {
    int k = idx >> 4, cq = (idx & 15) << 2;
    *(float4*)&B2_[k * L68 + cq] = *(const float4*)&ib[k * 64 + cq];
  }

  // phase 1: acc = sum_{p<s} L_i^p (L_s^p)^T
  float acc00 = 0, acc01 = 0, acc02 = 0, acc03 = 0, acc10 = 0, acc11 = 0, acc12 = 0, acc13 = 0;
  for (int p = 0; p < s; ++p) {
    __syncthreads();
    for (int idx = tid; idx < 1024; idx += 512) {
      int r = idx >> 4, kq = (idx & 15) << 2;
      float4 f = *(const float4*)&A[(size_t)(i * 64 + r) * K_N + p * 64 + kq];
      As_[(kq + 0) * L68 + r] = f.x; As_[(kq + 1) * L68 + r] = f.y;
      As_[(kq + 2) * L68 + r] = f.z; As_[(kq + 3) * L68 + r] = f.w;
      float4 g = *(const float4*)&A[(size_t)(s * 64 + r) * K_N + p * 64 + kq];
      Bs_[(kq + 0) * L68 + r] = g.x; Bs_[(kq + 1) * L68 + r] = g.y;
      Bs_[(kq + 2) * L68 + r] = g.z; Bs_[(kq + 3) * L68 + r] = g.w;
    }
    __syncthreads();
#pragma unroll 8
    for (int k = 0; k < 64; ++k) {
      float a0 = As_[k * L68 + r0], a1 = As_[k * L68 + r0 + 1];
      float4 bv = *(const float4*)&Bs_[k * L68 + c0];
      acc00 += a0 * bv.x; acc01 += a0 * bv.y; acc02 += a0 * bv.z; acc03 += a0 * bv.w;
      acc10 += a1 * bv.x; acc11 += a1 * bv.y; acc12 += a1 * bv.z; acc13 += a1 * bv.w;
    }
  }
  __syncthreads();
  // CT_[k][r] = C[r][k] = orig(i,s) - acc
  {
    float4 o0 = *(const float4*)&A[(size_t)(i * 64 + r0) * K_N + s * 64 + c0];
    float4 o1 = *(const float4*)&A[(size_t)(i * 64 + r0 + 1) * K_N + s * 64 + c0];
    CT_[(c0 + 0) * L68 + r0] = o0.x - acc00;
    CT_[(c0 + 1) * L68 + r0] = o0.y - acc01;
    CT_[(c0 + 2) * L68 + r0] = o0.z - acc02;
    CT_[(c0 + 3) * L68 + r0] = o0.w - acc03;
    CT_[(c0 + 0) * L68 + r0 + 1] = o1.x - acc10;
    CT_[(c0 + 1) * L68 + r0 + 1] = o1.y - acc11;
    CT_[(c0 + 2) * L68 + r0 + 1] = o1.z - acc12;
    CT_[(c0 + 3) * L68 + r0 + 1] = o1.w - acc13;
  }
  __syncthreads();
  // TRSM-as-GEMM: P[r][c] = sum_k C[r][k] * invL[c][k]
  float p00 = 0, p01 = 0, p02 = 0, p03 = 0, p10 = 0, p11 = 0, p12 = 0, p13 = 0;
#pragma unroll 8
  for (int k = 0; k < 64; ++k) {
    float a0 = CT_[k * L68 + r0], a1 = CT_[k * L68 + r0 + 1];
    float4 bv = *(const float4*)&B2_[k * L68 + c0];
    p00 += a0 * bv.x; p01 += a0 * bv.y; p02 += a0 * bv.z; p03 += a0 * bv.w;
    p10 += a1 * bv.x; p11 += a1 * bv.y; p12 += a1 * bv.z; p13 += a1 * bv.w;
  }
  float4 w0; w0.x = p00; w0.y = p01; w0.z = p02; w0.w = p03;
  float4 w1; w1.x = p10; w1.y = p11; w1.z = p12; w1.w = p13;
  *(float4*)&A[(size_t)(i * 64 + r0) * K_N + s * 64 + c0] = w0;
  *(float4*)&A[(size_t)(i * 64 + r0 + 1) * K_N + s * 64 + c0] = w1;

  if (blockIdx.x != 0) return;

  // ---- block 0 only: diag tile (s+1,s+1) self-update over p=0..s (incl. just-written P) ----
  float d00 = 0, d01 = 0, d02 = 0, d03 = 0, d10 = 0, d11 = 0, d12 = 0, d13 = 0;
  for (int p = 0; p <= s; ++p) {
    __syncthreads();                     // also drains the P stores before p==s re-read
    for (int idx = tid; idx < 1024; idx += 512) {
      int r = idx >> 4, kq = (idx & 15) << 2;
      float4 f = *(const float4*)&A[(size_t)(i * 64 + r) * K_N + p * 64 + kq];
      As_[(kq + 0) * L68 + r] = f.x; As_[(kq + 1) * L68 + r] = f.y;
      As_[(kq + 2) * L68 + r] = f.z; As_[(kq + 3) * L68 + r] = f.w;
    }
    __syncthreads();
#pragma unroll 8
    for (int k = 0; k < 64; ++k) {
      float a0 = As_[k * L68 + r0], a1 = As_[k * L68 + r0 + 1];
      float4 bv = *(const float4*)&As_[k * L68 + c0];
      d00 += a0 * bv.x; d01 += a0 * bv.y; d02 += a0 * bv.z; d03 += a0 * bv.w;
      d10 += a1 * bv.x; d11 += a1 * bv.y; d12 += a1 * bv.z; d13 += a1 * bv.w;
    }
  }
  __syncthreads();
  // smF (reuse Bs_): U = orig(s+1,s+1) - accD
  {
    float4 o0 = *(const float4*)&A[(size_t)(i * 64 + r0) * K_N + i * 64 + c0];
    float4 o1 = *(const float4*)&A[(size_t)(i * 64 + r0 + 1) * K_N + i * 64 + c0];
    Bs_[(r0 + 0) * L68 + c0 + 0] = o0.x - d00;
    Bs_[(r0 + 0) * L68 + c0 + 1] = o0.y - d01;
    Bs_[(r0 + 0) * L68 + c0 + 2] = o0.z - d02;
    Bs_[(r0 + 0) * L68 + c0 + 3] = o0.w - d03;
    Bs_[(r0 + 1) * L68 + c0 + 0] = o1.x - d10;
    Bs_[(r0 + 1) * L68 + c0 + 1] = o1.y - d11;
    Bs_[(r0 + 1) * L68 + c0 + 2] = o1.z - d12;
    Bs_[(r0 + 1) * L68 + c0 + 3] = o1.w - d13;
  }
  __syncthreads();
  if (tid < 64) {
    float a[64];
    factor64(Bs_, A, i * 64, &ld[m * 8 + s + 1], a, tid);
    if (s + 1 < 7) invert64(a, ib, tid);
  }
}

// ---------- combine ----------
__global__ void k_combine(const float* __restrict__ ld, const float* __restrict__ tr, float* __restrict__ out) {
  float l0 = 0.f, l1 = 0.f;
#pragma unroll
  for (int s = 0; s < 8; ++s) { l0 += ld[s]; l1 += ld[8 + s]; }
  out[0] = -l0 - l1 - (float)K_N + tr[0];
}

extern "C" void kernel_launch(void* const* d_in, const int* in_sizes, int n_in,
                              void* d_out, int out_size, void* d_ws, size_t ws_size,
                              hipStream_t stream) {
  const float* X  = (const float*)d_in[0];   // inputs  [V,128]
  const float* T  = (const float*)d_in[1];   // targets [K,K]
  const int*   ei = (const int*)d_in[2];     // edge_index [2,E]
  const float* P  = (const float*)d_in[3];   // pmat [K,V]
  float* out = (float*)d_out;
  char* ws = (char*)d_ws;

  // workspace layout (bytes); [0, 1314816) is one contiguous zero-memset region
  int*      cnt  = (int*)(ws + 0);
  float*    tr   = (float*)(ws + 16);
  float*    ld   = (float*)(ws + 32);            // 16 floats
  unsigned* htab = (unsigned*)(ws + 4096);       // 65536 u32 (256 KB) -> 266240
  float*    La   = (float*)(ws + 266240);        // K*K (1 MB) -> 1314816  (zeroed; lower filled)
  float*    Lw1  = (float*)(ws + 1314816);       // K*K (1 MB) -> 2363392  (copied from T in k_tr)
  int*      si   = (int*)(ws + 2363392);         // 16384 ints -> 2428928
  int*      sj   = (int*)(ws + 2428928);         // 16384 ints -> 2494464
  float*    sw   = (float*)(ws + 2494464);       // 16384 floats -> 2560000
  float*    ibuf = (float*)(ws + 2560000);       // 2 x 64x64 invL (32 KB) -> 2592768
  float*    PT   = (float*)(ws + 2592768);       // V*K floats (16 MB) -> 36147200

  hipMemsetAsync(ws, 0, 1314816, stream);        // cnt, tr, ld, htab, La

  k_tr<<<1280, 256, 0, stream>>>(P, PT, T, Lw1);
  k_edge<<<E_N / 32, 256, 0, stream>>>(X, ei, cnt, si, sj, sw, htab);
  k_syrk<<<dim3(36, NZ_SYRK), 256, 0, stream>>>(cnt, si, sj, sw, PT, La, T, tr);

  k_diag0<<<2, 512, 0, stream>>>(La, Lw1, ibuf, ld);
  for (int s = 0; s < 7; ++s)
    k_step<<<dim3(7 - s, 2), 512, 0, stream>>>(La, Lw1, ibuf, ld, s);
  k_combine<<<1, 1, 0, stream>>>(ld, tr, out);
}

// Round 8
// 900.807 us; speedup vs baseline: 1.1363x; 1.0722x over previous
//
#include <hip/hip_runtime.h>
#include <math.h>

#define V_N 8192
#define D_F 128
#define E_N 262144
#define K_N 512
#define DMAXF 0.5f
#define EPSW 1e-8f
#define EPSL 1e-5f
#define MAX_SE 16384
#define NZ_SYRK 24
#define L68 68

// ---------- transpose pmat (KxV)->PT (VxK) 64x64 float4 tiles, + Lw1 <- T copy ----------
__global__ __launch_bounds__(256) void k_tr(const float* __restrict__ P, float* __restrict__ PT,
                                            const float* __restrict__ T, float* __restrict__ Lw1) {
  int b = blockIdx.x, tid = threadIdx.x;
  if (b < 1024) {
    __shared__ float tl[64][65];
    int v0 = (b & 127) * 64, k0 = (b >> 7) * 64;
    int c4 = tid & 15, rq = tid >> 4;
#pragma unroll
    for (int rr = 0; rr < 4; ++rr) {
      int r = rq + 16 * rr;
      float4 f = *(const float4*)&P[(size_t)(k0 + r) * V_N + v0 + c4 * 4];
      tl[r][c4 * 4 + 0] = f.x; tl[r][c4 * 4 + 1] = f.y;
      tl[r][c4 * 4 + 2] = f.z; tl[r][c4 * 4 + 3] = f.w;
    }
    __syncthreads();
#pragma unroll
    for (int rr = 0; rr < 4; ++rr) {
      int r = rq + 16 * rr;   // v-local row
      float4 f;
      f.x = tl[c4 * 4 + 0][r]; f.y = tl[c4 * 4 + 1][r];
      f.z = tl[c4 * 4 + 2][r]; f.w = tl[c4 * 4 + 3][r];
      *(float4*)&PT[(size_t)(v0 + r) * K_N + k0 + c4 * 4] = f;
    }
  } else {
    int idx = (b - 1024) * 256 + tid;
    ((float4*)Lw1)[idx] = ((const float4*)T)[idx];
  }
}

// ---------- per-edge distance (8 lanes/edge), strong-edge dedup + compaction ----------
__global__ __launch_bounds__(256) void k_edge(const float* __restrict__ X, const int* __restrict__ ei,
                                              int* __restrict__ cnt, int* __restrict__ si,
                                              int* __restrict__ sj, float* __restrict__ sw,
                                              unsigned* __restrict__ htab) {
  int t = blockIdx.x * 256 + threadIdx.x;
  int e = t >> 3, lane = t & 7;
  int i = ei[e], j = ei[E_N + e];
  const float4* xi = (const float4*)(X + (size_t)i * D_F);
  const float4* xj = (const float4*)(X + (size_t)j * D_F);
  float4 A0 = xi[lane * 4 + 0], A1 = xi[lane * 4 + 1], A2 = xi[lane * 4 + 2], A3 = xi[lane * 4 + 3];
  float4 B0 = xj[lane * 4 + 0], B1 = xj[lane * 4 + 1], B2 = xj[lane * 4 + 2], B3 = xj[lane * 4 + 3];
  float d = 0.f, dx;
  dx = A0.x - B0.x; d += dx * dx; dx = A0.y - B0.y; d += dx * dx;
  dx = A0.z - B0.z; d += dx * dx; dx = A0.w - B0.w; d += dx * dx;
  dx = A1.x - B1.x; d += dx * dx; dx = A1.y - B1.y; d += dx * dx;
  dx = A1.z - B1.z; d += dx * dx; dx = A1.w - B1.w; d += dx * dx;
  dx = A2.x - B2.x; d += dx * dx; dx = A2.y - B2.y; d += dx * dx;
  dx = A2.z - B2.z; d += dx * dx; dx = A2.w - B2.w; d += dx * dx;
  dx = A3.x - B3.x; d += dx * dx; dx = A3.y - B3.y; d += dx * dx;
  dx = A3.z - B3.z; d += dx * dx; dx = A3.w - B3.w; d += dx * dx;
  d += __shfl_xor(d, 1);
  d += __shfl_xor(d, 2);
  d += __shfl_xor(d, 4);
  if (lane == 0 && d <= DMAXF) {
    float w = expf(-d);
    unsigned a = (unsigned)min(i, j), bb = (unsigned)max(i, j);
    unsigned key = a * 8192u + bb;         // key==0 impossible (a<b)
    unsigned h = (key * 2654435761u) >> 16;
    bool isnew = false;
    for (int probe = 0; probe < 65536; ++probe) {
      unsigned slot = (h + (unsigned)probe) & 65535u;
      unsigned prev = atomicCAS(&htab[slot], 0u, key);
      if (prev == 0u) { isnew = true; break; }
      if (prev == key) break;              // duplicate pair -> reference counts it once
    }
    if (isnew) {
      int p = atomicAdd(cnt, 1);
      if (p < MAX_SE) { si[p] = i; sj[p] = j; sw[p] = w; }
    }
  }
}

// ---------- La(lower) += Q^T Q + eps*I, Q rows = sqrt(w)*(PT[i]-PT[j]); fused trace epilogue ----------
__global__ __launch_bounds__(256) void k_syrk(const int* __restrict__ cnt, const int* __restrict__ si,
                                              const int* __restrict__ sj, const float* __restrict__ sw,
                                              const float* __restrict__ PT, float* __restrict__ La,
                                              const float* __restrict__ T, float* __restrict__ tr) {
  int p = blockIdx.x, bj = 0;
  while (p >= 8 - bj) { p -= 8 - bj; ++bj; }
  int bi = bj + p;
  int r0g = bi * 64, c0g = bj * 64;
  int m = min(*cnt, MAX_SE);
  int chunk = (m + NZ_SYRK - 1) / NZ_SYRK;
  int e0 = blockIdx.y * chunk;
  int e1 = min(m, e0 + chunk);

  __shared__ float As[16][68];
  __shared__ float Bs[16][68];
  int tid = threadIdx.x;
  int le = tid >> 4, f = tid & 15;
  int r0 = (tid >> 4) * 4, c0 = (tid & 15) * 4;
  float acc[4][4];
#pragma unroll
  for (int i = 0; i < 4; ++i)
#pragma unroll
    for (int j = 0; j < 4; ++j) acc[i][j] = 0.f;

  float w_ = 0.f;
  float4 ai = make_float4(0.f, 0.f, 0.f, 0.f), aj = ai, ci = ai, cj = ai;
  {
    int e = e0 + le;
    if (e < e1) {
      int i = si[e], j = sj[e];
      w_ = sw[e];
      const float* pi = &PT[(size_t)i * K_N];
      const float* pj = &PT[(size_t)j * K_N];
      ai = *(const float4*)(pi + r0g + f * 4);
      aj = *(const float4*)(pj + r0g + f * 4);
      if (bi != bj) {
        ci = *(const float4*)(pi + c0g + f * 4);
        cj = *(const float4*)(pj + c0g + f * 4);
      }
    }
  }

  for (int es = e0; es < e1; es += 16) {
    float sq = sqrtf(w_);
    float4 qa, qb;
    qa.x = sq * (ai.x - aj.x); qa.y = sq * (ai.y - aj.y);
    qa.z = sq * (ai.z - aj.z); qa.w = sq * (ai.w - aj.w);
    if (bi != bj) {
      qb.x = sq * (ci.x - cj.x); qb.y = sq * (ci.y - cj.y);
      qb.z = sq * (ci.z - cj.z); qb.w = sq * (ci.w - cj.w);
    } else {
      qb = qa;
    }
    __syncthreads();
    *(float4*)&As[le][f * 4] = qa;
    *(float4*)&Bs[le][f * 4] = qb;
    __syncthreads();

    {
      int e = es + 16 + le;
      w_ = 0.f;
      if (e < e1) {
        int i = si[e], j = sj[e];
        w_ = sw[e];
        const float* pi = &PT[(size_t)i * K_N];
        const float* pj = &PT[(size_t)j * K_N];
        ai = *(const float4*)(pi + r0g + f * 4);
        aj = *(const float4*)(pj + r0g + f * 4);
        if (bi != bj) {
          ci = *(const float4*)(pi + c0g + f * 4);
          cj = *(const float4*)(pj + c0g + f * 4);
        }
      }
    }

#pragma unroll
    for (int k = 0; k < 16; ++k) {
      float4 av = *(const float4*)&As[k][r0];
      float4 bv = *(const float4*)&Bs[k][c0];
      acc[0][0] += av.x * bv.x; acc[0][1] += av.x * bv.y; acc[0][2] += av.x * bv.z; acc[0][3] += av.x * bv.w;
      acc[1][0] += av.y * bv.x; acc[1][1] += av.y * bv.y; acc[1][2] += av.y * bv.z; acc[1][3] += av.y * bv.w;
      acc[2][0] += av.z * bv.x; acc[2][1] += av.z * bv.y; acc[2][2] += av.z * bv.z; acc[2][3] += av.z * bv.w;
      acc[3][0] += av.w * bv.x; acc[3][1] += av.w * bv.y; acc[3][2] += av.w * bv.z; acc[3][3] += av.w * bv.w;
    }
  }

  bool addeps = (blockIdx.y == 0) && (bi == bj);
  float tdot = 0.f;
#pragma unroll
  for (int i = 0; i < 4; ++i)
#pragma unroll
    for (int j = 0; j < 4; ++j) {
      float v = acc[i][j];
      int rg = r0g + r0 + i, cg = c0g + c0 + j;
      if (addeps && rg == cg) v += EPSL;
      atomicAdd(&La[(size_t)rg * K_N + cg], v);
      float sc = (bi != bj) ? 2.f : (rg == cg ? 1.f : (rg > cg ? 2.f : 0.f));
      if (sc != 0.f) tdot += sc * v * T[(size_t)rg * K_N + cg];
    }
  tdot += __shfl_down(tdot, 32); tdot += __shfl_down(tdot, 16); tdot += __shfl_down(tdot, 8);
  tdot += __shfl_down(tdot, 4);  tdot += __shfl_down(tdot, 2);  tdot += __shfl_down(tdot, 1);
  if ((tid & 63) == 0) atomicAdd(tr, tdot);
}

// ---------- k_fact(s): 1 wave per matrix. In-register 64x64 Cholesky of staged diag tile
// (s==0: A's tile (0,0); s>=1: dstage). Writes L rows to A diag tile, logdet part to ld,
// and (s<7) invL to ibuf in [c][k] layout (ib[c*64+k] = invL[k][c]). 64-thread block ->
// ~512 VGPR budget, a[64]+y[64] stay in registers (no scratch spill).
__global__ __launch_bounds__(64) void k_fact(float* La, float* Lw1, float* __restrict__ ibuf,
                                             const float* __restrict__ dstage,
                                             float* __restrict__ ld, int s) {
  int m = blockIdx.x;
  float* A = m ? Lw1 : La;
  int lane = threadIdx.x;
  int j0 = s * 64;
  float a[64];
  if (s == 0) {
#pragma unroll
    for (int q = 0; q < 16; ++q) {
      float4 f = *(const float4*)&A[(size_t)lane * K_N + q * 4];
      a[q * 4 + 0] = f.x; a[q * 4 + 1] = f.y; a[q * 4 + 2] = f.z; a[q * 4 + 3] = f.w;
    }
  } else {
    const float* U = dstage + m * 4096;
#pragma unroll
    for (int q = 0; q < 16; ++q) {
      float4 f = *(const float4*)&U[lane * 64 + q * 4];
      a[q * 4 + 0] = f.x; a[q * 4 + 1] = f.y; a[q * 4 + 2] = f.z; a[q * 4 + 3] = f.w;
    }
  }
  float ls = 0.f;
#pragma unroll
  for (int c = 0; c < 64; ++c) {
    float dc = __shfl(a[c], c);          // fully-updated diagonal = L_cc^2
    ls += logf(dc);
    float rs = rsqrtf(dc);
    a[c] *= rs;
#pragma unroll
    for (int k = c + 1; k < 64; ++k)
      a[k] -= a[c] * __shfl(a[c], k);
  }
#pragma unroll
  for (int q = 0; q < 16; ++q) {
    float4 f;
    f.x = a[q * 4 + 0]; f.y = a[q * 4 + 1]; f.z = a[q * 4 + 2]; f.w = a[q * 4 + 3];
    *(float4*)&A[(size_t)(j0 + lane) * K_N + j0 + q * 4] = f;
  }
  if (lane == 0) ld[m * 8 + s] = ls;

  if (s < 7) {
    float* ib = ibuf + m * 4096;
    float y[64];                          // lane = column c of invL
#pragma unroll
    for (int k = 0; k < 64; ++k) {
      float t = (k == lane) ? 1.f : 0.f;
#pragma unroll
      for (int mm = 0; mm < k; ++mm)
        t -= __shfl(a[mm], k) * y[mm];   // L[k][mm]
      y[k] = t / __shfl(a[k], k);        // / L[k][k]
    }
#pragma unroll
    for (int q = 0; q < 16; ++q) {
      float4 f;
      f.x = y[q * 4 + 0]; f.y = y[q * 4 + 1]; f.z = y[q * 4 + 2]; f.w = y[q * 4 + 3];
      *(float4*)&ib[lane * 64 + q * 4] = f;
    }
  }
}

// ---------- k_step(s): GEMM-only left-looking column update + TRSM-as-GEMM.
// Block (blockIdx.x, matrix blockIdx.y) handles row-block i = s+1+blockIdx.x of column s.
// Block 0 also self-updates diag tile (s+1,s+1) (using in-LDS P for p==s) -> dstage.
__global__ __launch_bounds__(256) void k_step(float* La, float* Lw1, const float* __restrict__ ibuf,
                                              float* __restrict__ dstage, int s) {
  int m = blockIdx.y;
  float* A = m ? Lw1 : La;
  const float* ib = ibuf + m * 4096;
  int tid = threadIdx.x;
  int i = s + 1 + blockIdx.x;
  int r0 = (tid >> 4) * 4, c0 = (tid & 15) * 4;
  __shared__ float As_[64 * L68];
  __shared__ float Bs_[64 * L68];
  __shared__ float B2_[64 * L68];

  // stage invL: B2_[k][c] = ib[k*64+c] (= invL[c][k])
  for (int idx = tid; idx < 1024; idx += 256) {
    int k = idx >> 4, cq = (idx & 15) << 2;
    *(float4*)&B2_[k * L68 + cq] = *(const float4*)&ib[k * 64 + cq];
  }

  // phase 1: acc = sum_{p<s} L(i,p) L(s,p)^T
  float acc[4][4];
#pragma unroll
  for (int ii = 0; ii < 4; ++ii)
#pragma unroll
    for (int jj = 0; jj < 4; ++jj) acc[ii][jj] = 0.f;
  for (int p = 0; p < s; ++p) {
    __syncthreads();
    for (int idx = tid; idx < 1024; idx += 256) {
      int r = idx >> 4, kq = (idx & 15) << 2;
      float4 f = *(const float4*)&A[(size_t)(i * 64 + r) * K_N + p * 64 + kq];
      As_[(kq + 0) * L68 + r] = f.x; As_[(kq + 1) * L68 + r] = f.y;
      As_[(kq + 2) * L68 + r] = f.z; As_[(kq + 3) * L68 + r] = f.w;
      float4 g = *(const float4*)&A[(size_t)(s * 64 + r) * K_N + p * 64 + kq];
      Bs_[(kq + 0) * L68 + r] = g.x; Bs_[(kq + 1) * L68 + r] = g.y;
      Bs_[(kq + 2) * L68 + r] = g.z; Bs_[(kq + 3) * L68 + r] = g.w;
    }
    __syncthreads();
#pragma unroll 8
    for (int k = 0; k < 64; ++k) {
      float4 av = *(const float4*)&As_[k * L68 + r0];
      float4 bv = *(const float4*)&Bs_[k * L68 + c0];
      acc[0][0] += av.x * bv.x; acc[0][1] += av.x * bv.y; acc[0][2] += av.x * bv.z; acc[0][3] += av.x * bv.w;
      acc[1][0] += av.y * bv.x; acc[1][1] += av.y * bv.y; acc[1][2] += av.y * bv.z; acc[1][3] += av.y * bv.w;
      acc[2][0] += av.z * bv.x; acc[2][1] += av.z * bv.y; acc[2][2] += av.z * bv.z; acc[2][3] += av.z * bv.w;
      acc[3][0] += av.w * bv.x; acc[3][1] += av.w * bv.y; acc[3][2] += av.w * bv.z; acc[3][3] += av.w * bv.w;
    }
  }
  __syncthreads();
  // C = orig A(i,s) - acc, store transposed into As_: As_[k][r] = C[r][k]
#pragma unroll
  for (int ii = 0; ii < 4; ++ii) {
    float4 o = *(const float4*)&A[(size_t)(i * 64 + r0 + ii) * K_N + s * 64 + c0];
    As_[(c0 + 0) * L68 + r0 + ii] = o.x - acc[ii][0];
    As_[(c0 + 1) * L68 + r0 + ii] = o.y - acc[ii][1];
    As_[(c0 + 2) * L68 + r0 + ii] = o.z - acc[ii][2];
    As_[(c0 + 3) * L68 + r0 + ii] = o.w - acc[ii][3];
  }
  __syncthreads();
  // TRSM-as-GEMM: P[r][c] = sum_k C[r][k] * invL[c][k]
  float pa[4][4];
#pragma unroll
  for (int ii = 0; ii < 4; ++ii)
#pragma unroll
    for (int jj = 0; jj < 4; ++jj) pa[ii][jj] = 0.f;
#pragma unroll 8
  for (int k = 0; k < 64; ++k) {
    float4 av = *(const float4*)&As_[k * L68 + r0];
    float4 bv = *(const float4*)&B2_[k * L68 + c0];
    pa[0][0] += av.x * bv.x; pa[0][1] += av.x * bv.y; pa[0][2] += av.x * bv.z; pa[0][3] += av.x * bv.w;
    pa[1][0] += av.y * bv.x; pa[1][1] += av.y * bv.y; pa[1][2] += av.y * bv.z; pa[1][3] += av.y * bv.w;
    pa[2][0] += av.z * bv.x; pa[2][1] += av.z * bv.y; pa[2][2] += av.z * bv.z; pa[2][3] += av.z * bv.w;
    pa[3][0] += av.w * bv.x; pa[3][1] += av.w * bv.y; pa[3][2] += av.w * bv.z; pa[3][3] += av.w * bv.w;
  }
#pragma unroll
  for (int ii = 0; ii < 4; ++ii) {
    float4 w;
    w.x = pa[ii][0]; w.y = pa[ii][1]; w.z = pa[ii][2]; w.w = pa[ii][3];
    *(float4*)&A[(size_t)(i * 64 + r0 + ii) * K_N + s * 64 + c0] = w;
  }

  if (blockIdx.x != 0) return;

  // ---- block 0 only: diag tile (s+1,s+1) self-update over p=0..s ----
  float da[4][4];
#pragma unroll
  for (int ii = 0; ii < 4; ++ii)
#pragma unroll
    for (int jj = 0; jj < 4; ++jj) da[ii][jj] = 0.f;
  for (int p = 0; p < s; ++p) {
    __syncthreads();
    for (int idx = tid; idx < 1024; idx += 256) {
      int r = idx >> 4, kq = (idx & 15) << 2;
      float4 f = *(const float4*)&A[(size_t)(i * 64 + r) * K_N + p * 64 + kq];
      Bs_[(kq + 0) * L68 + r] = f.x; Bs_[(kq + 1) * L68 + r] = f.y;
      Bs_[(kq + 2) * L68 + r] = f.z; Bs_[(kq + 3) * L68 + r] = f.w;
    }
    __syncthreads();
#pragma unroll 8
    for (int k = 0; k < 64; ++k) {
      float4 av = *(const float4*)&Bs_[k * L68 + r0];
      float4 bv = *(const float4*)&Bs_[k * L68 + c0];
      da[0][0] += av.x * bv.x; da[0][1] += av.x * bv.y; da[0][2] += av.x * bv.z; da[0][3] += av.x * bv.w;
      da[1][0] += av.y * bv.x; da[1][1] += av.y * bv.y; da[1][2] += av.y * bv.z; da[1][3] += av.y * bv.w;
      da[2][0] += av.z * bv.x; da[2][1] += av.z * bv.y; da[2][2] += av.z * bv.z; da[2][3] += av.z * bv.w;
      da[3][0] += av.w * bv.x; da[3][1] += av.w * bv.y; da[3][2] += av.w * bv.z; da[3][3] += av.w * bv.w;
    }
  }
  // p == s: use just-computed P (registers) staged transposed into Bs_
  __syncthreads();
#pragma unroll
  for (int ii = 0; ii < 4; ++ii) {
    Bs_[(c0 + 0) * L68 + r0 + ii] = pa[ii][0];
    Bs_[(c0 + 1) * L68 + r0 + ii] = pa[ii][1];
    Bs_[(c0 + 2) * L68 + r0 + ii] = pa[ii][2];
    Bs_[(c0 + 3) * L68 + r0 + ii] = pa[ii][3];
  }
  __syncthreads();
#pragma unroll 8
  for (int k = 0; k < 64; ++k) {
    float4 av = *(const float4*)&Bs_[k * L68 + r0];
    float4 bv = *(const float4*)&Bs_[k * L68 + c0];
    da[0][0] += av.x * bv.x; da[0][1] += av.x * bv.y; da[0][2] += av.x * bv.z; da[0][3] += av.x * bv.w;
    da[1][0] += av.y * bv.x; da[1][1] += av.y * bv.y; da[1][2] += av.y * bv.z; da[1][3] += av.y * bv.w;
    da[2][0] += av.z * bv.x; da[2][1] += av.z * bv.y; da[2][2] += av.z * bv.z; da[2][3] += av.z * bv.w;
    da[3][0] += av.w * bv.x; da[3][1] += av.w * bv.y; da[3][2] += av.w * bv.z; da[3][3] += av.w * bv.w;
  }
  // U = orig A(i,i) - da  -> dstage
  float* U = dstage + m * 4096;
#pragma unroll
  for (int ii = 0; ii < 4; ++ii) {
    float4 o = *(const float4*)&A[(size_t)(i * 64 + r0 + ii) * K_N + i * 64 + c0];
    float4 w;
    w.x = o.x - da[ii][0]; w.y = o.y - da[ii][1];
    w.z = o.z - da[ii][2]; w.w = o.w - da[ii][3];
    *(float4*)&U[(r0 + ii) * 64 + c0] = w;
  }
}

// ---------- combine ----------
__global__ void k_combine(const float* __restrict__ ld, const float* __restrict__ tr, float* __restrict__ out) {
  float l0 = 0.f, l1 = 0.f;
#pragma unroll
  for (int s = 0; s < 8; ++s) { l0 += ld[s]; l1 += ld[8 + s]; }
  out[0] = -l0 - l1 - (float)K_N + tr[0];
}

extern "C" void kernel_launch(void* const* d_in, const int* in_sizes, int n_in,
                              void* d_out, int out_size, void* d_ws, size_t ws_size,
                              hipStream_t stream) {
  const float* X  = (const float*)d_in[0];   // inputs  [V,128]
  const float* T  = (const float*)d_in[1];   // targets [K,K]
  const int*   ei = (const int*)d_in[2];     // edge_index [2,E]
  const float* P  = (const float*)d_in[3];   // pmat [K,V]
  float* out = (float*)d_out;
  char* ws = (char*)d_ws;

  // workspace layout (bytes); [0, 1314816) is one contiguous zero-memset region
  int*      cnt    = (int*)(ws + 0);
  float*    tr     = (float*)(ws + 16);
  float*    ld     = (float*)(ws + 32);           // 16 floats
  unsigned* htab   = (unsigned*)(ws + 4096);      // 65536 u32 (256 KB) -> 266240
  float*    La     = (float*)(ws + 266240);       // K*K (1 MB) -> 1314816 (zeroed; lower filled)
  float*    Lw1    = (float*)(ws + 1314816);      // K*K (1 MB) -> 2363392 (copied from T in k_tr)
  int*      si     = (int*)(ws + 2363392);        // 16384 ints -> 2428928
  int*      sj     = (int*)(ws + 2428928);        // 16384 ints -> 2494464
  float*    sw     = (float*)(ws + 2494464);      // 16384 floats -> 2560000
  float*    ibuf   = (float*)(ws + 2560000);      // 2 x 64x64 invL (32 KB) -> 2592768
  float*    dstage = (float*)(ws + 2592768);      // 2 x 64x64 staged diag (32 KB) -> 2625536
  float*    PT     = (float*)(ws + 2625536);      // V*K floats (16 MB) -> 20180000

  hipMemsetAsync(ws, 0, 1314816, stream);         // cnt, tr, ld, htab, La

  k_tr<<<1280, 256, 0, stream>>>(P, PT, T, Lw1);
  k_edge<<<E_N / 32, 256, 0, stream>>>(X, ei, cnt, si, sj, sw, htab);
  k_syrk<<<dim3(36, NZ_SYRK), 256, 0, stream>>>(cnt, si, sj, sw, PT, La, T, tr);

  k_fact<<<2, 64, 0, stream>>>(La, Lw1, ibuf, dstage, ld, 0);
  for (int s = 0; s < 7; ++s) {
    k_step<<<dim3(7 - s, 2), 256, 0, stream>>>(La, Lw1, ibuf, dstage, s);
    k_fact<<<2, 64, 0, stream>>>(La, Lw1, ibuf, dstage, ld, s + 1);
  }
  k_combine<<<1, 1, 0, stream>>>(ld, tr, out);
}

// Round 10
// 549.772 us; speedup vs baseline: 1.8618x; 1.6385x over previous
//
#include <hip/hip_runtime.h>
#include <math.h>

#define V_N 8192
#define D_F 128
#define E_N 262144
#define K_N 512
#define DMAXF 0.5f
#define EPSW 1e-8f
#define EPSL 1e-5f
#define MAX_SE 16384
#define NZ_SYRK 24
#define L68 68

#define NB_TR 1024
#define NB_CP 256
#define NB_ED (E_N / 32)

// ---------- fused pre-pass: transpose pmat (KxV)->PT (VxK) | Lw1 <- T | edge dedup ----------
__global__ __launch_bounds__(256) void k_pre(const float* __restrict__ P, float* __restrict__ PT,
                                             const float* __restrict__ X, const int* __restrict__ ei,
                                             int* __restrict__ cnt, int* __restrict__ si,
                                             int* __restrict__ sj, float* __restrict__ sw,
                                             unsigned* __restrict__ htab,
                                             const float* __restrict__ T, float* __restrict__ Lw1) {
  int b = blockIdx.x, tid = threadIdx.x;
  if (b < NB_TR) {
    __shared__ float tl[64][65];
    int v0 = (b & 127) * 64, k0 = (b >> 7) * 64;
    int c4 = tid & 15, rq = tid >> 4;
#pragma unroll
    for (int rr = 0; rr < 4; ++rr) {
      int r = rq + 16 * rr;
      float4 f = *(const float4*)&P[(size_t)(k0 + r) * V_N + v0 + c4 * 4];
      tl[r][c4 * 4 + 0] = f.x; tl[r][c4 * 4 + 1] = f.y;
      tl[r][c4 * 4 + 2] = f.z; tl[r][c4 * 4 + 3] = f.w;
    }
    __syncthreads();
#pragma unroll
    for (int rr = 0; rr < 4; ++rr) {
      int r = rq + 16 * rr;   // v-local row
      float4 f;
      f.x = tl[c4 * 4 + 0][r]; f.y = tl[c4 * 4 + 1][r];
      f.z = tl[c4 * 4 + 2][r]; f.w = tl[c4 * 4 + 3][r];
      *(float4*)&PT[(size_t)(v0 + r) * K_N + k0 + c4 * 4] = f;
    }
  } else if (b < NB_TR + NB_CP) {
    int idx = (b - NB_TR) * 256 + tid;
    ((float4*)Lw1)[idx] = ((const float4*)T)[idx];
  } else {
    // per-edge distance (8 lanes/edge), strong-edge dedup + compaction
    int t = (b - NB_TR - NB_CP) * 256 + tid;
    int e = t >> 3, lane = t & 7;
    int i = ei[e], j = ei[E_N + e];
    const float4* xi = (const float4*)(X + (size_t)i * D_F);
    const float4* xj = (const float4*)(X + (size_t)j * D_F);
    float4 A0 = xi[lane * 4 + 0], A1 = xi[lane * 4 + 1], A2 = xi[lane * 4 + 2], A3 = xi[lane * 4 + 3];
    float4 B0 = xj[lane * 4 + 0], B1 = xj[lane * 4 + 1], B2 = xj[lane * 4 + 2], B3 = xj[lane * 4 + 3];
    float d = 0.f, dx;
    dx = A0.x - B0.x; d += dx * dx; dx = A0.y - B0.y; d += dx * dx;
    dx = A0.z - B0.z; d += dx * dx; dx = A0.w - B0.w; d += dx * dx;
    dx = A1.x - B1.x; d += dx * dx; dx = A1.y - B1.y; d += dx * dx;
    dx = A1.z - B1.z; d += dx * dx; dx = A1.w - B1.w; d += dx * dx;
    dx = A2.x - B2.x; d += dx * dx; dx = A2.y - B2.y; d += dx * dx;
    dx = A2.z - B2.z; d += dx * dx; dx = A2.w - B2.w; d += dx * dx;
    dx = A3.x - B3.x; d += dx * dx; dx = A3.y - B3.y; d += dx * dx;
    dx = A3.z - B3.z; d += dx * dx; dx = A3.w - B3.w; d += dx * dx;
    d += __shfl_xor(d, 1);
    d += __shfl_xor(d, 2);
    d += __shfl_xor(d, 4);
    if (lane == 0 && d <= DMAXF) {
      float w = expf(-d);
      unsigned a = (unsigned)min(i, j), bb = (unsigned)max(i, j);
      unsigned key = a * 8192u + bb;         // key==0 impossible (a<b)
      unsigned h = (key * 2654435761u) >> 16;
      bool isnew = false;
      for (int probe = 0; probe < 65536; ++probe) {
        unsigned slot = (h + (unsigned)probe) & 65535u;
        unsigned prev = atomicCAS(&htab[slot], 0u, key);
        if (prev == 0u) { isnew = true; break; }
        if (prev == key) break;              // duplicate pair -> reference counts it once
      }
      if (isnew) {
        int p = atomicAdd(cnt, 1);
        if (p < MAX_SE) { si[p] = i; sj[p] = j; sw[p] = w; }
      }
    }
  }
}

// ---------- La(lower) += Q^T Q + eps*I, Q rows = sqrt(w)*(PT[i]-PT[j]); fused trace epilogue ----------
__global__ __launch_bounds__(256) void k_syrk(const int* __restrict__ cnt, const int* __restrict__ si,
                                              const int* __restrict__ sj, const float* __restrict__ sw,
                                              const float* __restrict__ PT, float* __restrict__ La,
                                              const float* __restrict__ T, float* __restrict__ tr) {
  int p = blockIdx.x, bj = 0;
  while (p >= 8 - bj) { p -= 8 - bj; ++bj; }
  int bi = bj + p;
  int r0g = bi * 64, c0g = bj * 64;
  int m = min(*cnt, MAX_SE);
  int chunk = (m + NZ_SYRK - 1) / NZ_SYRK;
  int e0 = blockIdx.y * chunk;
  int e1 = min(m, e0 + chunk);

  __shared__ float As[16][68];
  __shared__ float Bs[16][68];
  int tid = threadIdx.x;
  int le = tid >> 4, f = tid & 15;
  int r0 = (tid >> 4) * 4, c0 = (tid & 15) * 4;
  float acc[4][4];
#pragma unroll
  for (int i = 0; i < 4; ++i)
#pragma unroll
    for (int j = 0; j < 4; ++j) acc[i][j] = 0.f;

  float w_ = 0.f;
  float4 ai = make_float4(0.f, 0.f, 0.f, 0.f), aj = ai, ci = ai, cj = ai;
  {
    int e = e0 + le;
    if (e < e1) {
      int i = si[e], j = sj[e];
      w_ = sw[e];
      const float* pi = &PT[(size_t)i * K_N];
      const float* pj = &PT[(size_t)j * K_N];
      ai = *(const float4*)(pi + r0g + f * 4);
      aj = *(const float4*)(pj + r0g + f * 4);
      if (bi != bj) {
        ci = *(const float4*)(pi + c0g + f * 4);
        cj = *(const float4*)(pj + c0g + f * 4);
      }
    }
  }

  for (int es = e0; es < e1; es += 16) {
    float sq = sqrtf(w_);
    float4 qa, qb;
    qa.x = sq * (ai.x - aj.x); qa.y = sq * (ai.y - aj.y);
    qa.z = sq * (ai.z - aj.z); qa.w = sq * (ai.w - aj.w);
    if (bi != bj) {
      qb.x = sq * (ci.x - cj.x); qb.y = sq * (ci.y - cj.y);
      qb.z = sq * (ci.z - cj.z); qb.w = sq * (ci.w - cj.w);
    } else {
      qb = qa;
    }
    __syncthreads();
    *(float4*)&As[le][f * 4] = qa;
    *(float4*)&Bs[le][f * 4] = qb;
    __syncthreads();

    {
      int e = es + 16 + le;
      w_ = 0.f;
      if (e < e1) {
        int i = si[e], j = sj[e];
        w_ = sw[e];
        const float* pi = &PT[(size_t)i * K_N];
        const float* pj = &PT[(size_t)j * K_N];
        ai = *(const float4*)(pi + r0g + f * 4);
        aj = *(const float4*)(pj + r0g + f * 4);
        if (bi != bj) {
          ci = *(const float4*)(pi + c0g + f * 4);
          cj = *(const float4*)(pj + c0g + f * 4);
        }
      }
    }

#pragma unroll
    for (int k = 0; k < 16; ++k) {
      float4 av = *(const float4*)&As[k][r0];
      float4 bv = *(const float4*)&Bs[k][c0];
      acc[0][0] += av.x * bv.x; acc[0][1] += av.x * bv.y; acc[0][2] += av.x * bv.z; acc[0][3] += av.x * bv.w;
      acc[1][0] += av.y * bv.x; acc[1][1] += av.y * bv.y; acc[1][2] += av.y * bv.z; acc[1][3] += av.y * bv.w;
      acc[2][0] += av.z * bv.x; acc[2][1] += av.z * bv.y; acc[2][2] += av.z * bv.z; acc[2][3] += av.z * bv.w;
      acc[3][0] += av.w * bv.x; acc[3][1] += av.w * bv.y; acc[3][2] += av.w * bv.z; acc[3][3] += av.w * bv.w;
    }
  }

  bool addeps = (blockIdx.y == 0) && (bi == bj);
  float tdot = 0.f;
#pragma unroll
  for (int i = 0; i < 4; ++i)
#pragma unroll
    for (int j = 0; j < 4; ++j) {
      float v = acc[i][j];
      int rg = r0g + r0 + i, cg = c0g + c0 + j;
      if (addeps && rg == cg) v += EPSL;
      atomicAdd(&La[(size_t)rg * K_N + cg], v);
      float sc = (bi != bj) ? 2.f : (rg == cg ? 1.f : (rg > cg ? 2.f : 0.f));
      if (sc != 0.f) tdot += sc * v * T[(size_t)rg * K_N + cg];
    }
  tdot += __shfl_down(tdot, 32); tdot += __shfl_down(tdot, 16); tdot += __shfl_down(tdot, 8);
  tdot += __shfl_down(tdot, 4);  tdot += __shfl_down(tdot, 2);  tdot += __shfl_down(tdot, 1);
  if ((tid & 63) == 0) atomicAdd(tr, tdot);
}

// ---------- in-register 64x64 Cholesky by one wave, source = LDS tile (stride L68) ----------
__device__ __forceinline__ void factor64_lds(const float* __restrict__ smF, float* A, int j0,
                                             float* __restrict__ ldout, int lane) {
  float a[64];
#pragma unroll
  for (int qq = 0; qq < 16; ++qq) {
    float4 f = *(const float4*)&smF[lane * L68 + qq * 4];
    a[qq * 4 + 0] = f.x; a[qq * 4 + 1] = f.y; a[qq * 4 + 2] = f.z; a[qq * 4 + 3] = f.w;
  }
  float ls = 0.f;
#pragma unroll
  for (int c = 0; c < 64; ++c) {
    float dc = __shfl(a[c], c);          // fully-updated diagonal = L_cc^2
    ls += logf(dc);
    float rs = rsqrtf(dc);
    a[c] *= rs;
#pragma unroll
    for (int k = c + 1; k < 64; ++k)
      a[k] -= a[c] * __shfl(a[c], k);
  }
#pragma unroll
  for (int qq = 0; qq < 16; ++qq) {
    float4 f;
    f.x = a[qq * 4 + 0]; f.y = a[qq * 4 + 1]; f.z = a[qq * 4 + 2]; f.w = a[qq * 4 + 3];
    *(float4*)&A[(size_t)(j0 + lane) * K_N + j0 + qq * 4] = f;
  }
  if (lane == 0) *ldout = ls;
}

// ---------- k_fact0: factor tile (0,0) of both matrices (1 wave each) ----------
__global__ __launch_bounds__(64) void k_fact0(float* La, float* Lw1, float* __restrict__ ld) {
  int m = blockIdx.x;
  float* A = m ? Lw1 : La;
  int lane = threadIdx.x;
  float a[64];
#pragma unroll
  for (int qq = 0; qq < 16; ++qq) {
    float4 f = *(const float4*)&A[(size_t)lane * K_N + qq * 4];
    a[qq * 4 + 0] = f.x; a[qq * 4 + 1] = f.y; a[qq * 4 + 2] = f.z; a[qq * 4 + 3] = f.w;
  }
  float ls = 0.f;
#pragma unroll
  for (int c = 0; c < 64; ++c) {
    float dc = __shfl(a[c], c);
    ls += logf(dc);
    float rs = rsqrtf(dc);
    a[c] *= rs;
#pragma unroll
    for (int k = c + 1; k < 64; ++k)
      a[k] -= a[c] * __shfl(a[c], k);
  }
#pragma unroll
  for (int qq = 0; qq < 16; ++qq) {
    float4 f;
    f.x = a[qq * 4 + 0]; f.y = a[qq * 4 + 1]; f.z = a[qq * 4 + 2]; f.w = a[qq * 4 + 3];
    *(float4*)&A[(size_t)lane * K_N + qq * 4] = f;
  }
  if (lane == 0) ld[m * 8] = ls;
}

// ---------- k_cstep(s): one dispatch per panel step. Each lower-tri trailing pair
// (i,j >= s+1, i >= j): redundant in-block TRSM of column tiles C(i,s), C(j,s) vs L(s,s),
// then tile(i,j) -= P_i P_j^T. ONLY the i==j==s+1 block instead factors its updated
// tile in-register (wave 0) and writes the logdet part. Diag pairs with i==j>s+1 take
// the normal update path (they must NOT be factored yet). Column panels below the
// diagonal are never finalized (nothing downstream consumes them).
__global__ __launch_bounds__(256, 1) void k_cstep(float* La, float* Lw1, float* __restrict__ ld, int s) {
  int m = blockIdx.y;
  float* A = m ? Lw1 : La;
  int tid = threadIdx.x;
  int nt2 = 7 - s;
  int q = blockIdx.x, lbj = 0;
  while (q >= nt2 - lbj) { q -= nt2 - lbj; ++lbj; }
  int lbi = lbj + q;
  int i = s + 1 + lbi, j = s + 1 + lbj;

  __shared__ float LT[64 * L68];       // LT[c][k] = L(s,s)[k][c]; later reused as smF
  __shared__ float PiT[64 * L68];      // PiT[k][r] = P_i[r][k]
  __shared__ float PjT[64 * L68];
  __shared__ float rinv[64];

  // stage L(s,s) transposed
  for (int idx = tid; idx < 1024; idx += 256) {
    int r = idx >> 4, cq = (idx & 15) << 2;
    float4 f = *(const float4*)&A[(size_t)(s * 64 + r) * K_N + s * 64 + cq];
    LT[(cq + 0) * L68 + r] = f.x; LT[(cq + 1) * L68 + r] = f.y;
    LT[(cq + 2) * L68 + r] = f.z; LT[(cq + 3) * L68 + r] = f.w;
  }
  __syncthreads();
  if (tid < 64) rinv[tid] = 1.0f / LT[tid * L68 + tid];
  __syncthreads();

  // TRSM: wave 0 -> rows of C(i,s); wave 1 -> rows of C(j,s) (skip if i==j)
  {
    int w = tid >> 6, r = tid & 63;
    bool act = (w == 0) || (w == 1 && i != j);
    if (act) {
      int rowblk = (w == 0) ? i : j;
      const float* src = &A[(size_t)(rowblk * 64 + r) * K_N + s * 64];
      float x[64];
#pragma unroll
      for (int qq = 0; qq < 16; ++qq) {
        float4 f = *(const float4*)(src + qq * 4);
        x[qq * 4 + 0] = f.x; x[qq * 4 + 1] = f.y; x[qq * 4 + 2] = f.z; x[qq * 4 + 3] = f.w;
      }
#pragma unroll
      for (int c = 0; c < 64; ++c) {
        float xc = x[c] * rinv[c];
        x[c] = xc;
#pragma unroll
        for (int k = c + 1; k < 64; ++k)
          x[k] -= xc * LT[c * L68 + k];
      }
      float* dst = (w == 0) ? PiT : PjT;
#pragma unroll
      for (int k = 0; k < 64; ++k) dst[k * L68 + r] = x[k];
    }
  }
  __syncthreads();

  // GEMM: acc = P_i @ P_j^T  (P_j = P_i if diag pair)
  const float* Bp = (i == j) ? PiT : PjT;
  int r0 = (tid >> 4) * 4, c0 = (tid & 15) * 4;
  float acc[4][4];
#pragma unroll
  for (int ii = 0; ii < 4; ++ii)
#pragma unroll
    for (int jj = 0; jj < 4; ++jj) acc[ii][jj] = 0.f;
#pragma unroll 8
  for (int k = 0; k < 64; ++k) {
    float4 av = *(const float4*)&PiT[k * L68 + r0];
    float4 bv = *(const float4*)&Bp[k * L68 + c0];
    acc[0][0] += av.x * bv.x; acc[0][1] += av.x * bv.y; acc[0][2] += av.x * bv.z; acc[0][3] += av.x * bv.w;
    acc[1][0] += av.y * bv.x; acc[1][1] += av.y * bv.y; acc[1][2] += av.y * bv.z; acc[1][3] += av.y * bv.w;
    acc[2][0] += av.z * bv.x; acc[2][1] += av.z * bv.y; acc[2][2] += av.z * bv.z; acc[2][3] += av.z * bv.w;
    acc[3][0] += av.w * bv.x; acc[3][1] += av.w * bv.y; acc[3][2] += av.w * bv.z; acc[3][3] += av.w * bv.w;
  }

  if (i != j || i > s + 1) {
    // trailing update: tile(i,j) -= acc   (includes diag tiles i==j>s+1 — NOT factored yet)
#pragma unroll
    for (int ii = 0; ii < 4; ++ii) {
      float* cp = &A[(size_t)(i * 64 + r0 + ii) * K_N + j * 64 + c0];
      float4 o = *(const float4*)cp;
      float4 wv;
      wv.x = o.x - acc[ii][0]; wv.y = o.y - acc[ii][1];
      wv.z = o.z - acc[ii][2]; wv.w = o.w - acc[ii][3];
      *(float4*)cp = wv;
    }
  } else {
    // the next-panel diag block (i == j == s+1): updated tile -> smF (reuse LT), factor
#pragma unroll
    for (int ii = 0; ii < 4; ++ii) {
      const float* cp = &A[(size_t)(i * 64 + r0 + ii) * K_N + i * 64 + c0];
      float4 o = *(const float4*)cp;
      LT[(r0 + ii) * L68 + c0 + 0] = o.x - acc[ii][0];
      LT[(r0 + ii) * L68 + c0 + 1] = o.y - acc[ii][1];
      LT[(r0 + ii) * L68 + c0 + 2] = o.z - acc[ii][2];
      LT[(r0 + ii) * L68 + c0 + 3] = o.w - acc[ii][3];
    }
    __syncthreads();
    if (tid < 64)
      factor64_lds(LT, A, i * 64, &ld[m * 8 + s + 1], tid);
  }
}

// ---------- combine ----------
__global__ void k_combine(const float* __restrict__ ld, const float* __restrict__ tr, float* __restrict__ out) {
  float l0 = 0.f, l1 = 0.f;
#pragma unroll
  for (int s = 0; s < 8; ++s) { l0 += ld[s]; l1 += ld[8 + s]; }
  out[0] = -l0 - l1 - (float)K_N + tr[0];
}

extern "C" void kernel_launch(void* const* d_in, const int* in_sizes, int n_in,
                              void* d_out, int out_size, void* d_ws, size_t ws_size,
                              hipStream_t stream) {
  const float* X  = (const float*)d_in[0];   // inputs  [V,128]
  const float* T  = (const float*)d_in[1];   // targets [K,K]
  const int*   ei = (const int*)d_in[2];     // edge_index [2,E]
  const float* P  = (const float*)d_in[3];   // pmat [K,V]
  float* out = (float*)d_out;
  char* ws = (char*)d_ws;

  // workspace layout (bytes); [0, 1314816) is one contiguous zero-memset region
  int*      cnt    = (int*)(ws + 0);
  float*    tr     = (float*)(ws + 16);
  float*    ld     = (float*)(ws + 32);           // 16 floats
  unsigned* htab   = (unsigned*)(ws + 4096);      // 65536 u32 (256 KB) -> 266240
  float*    La     = (float*)(ws + 266240);       // K*K (1 MB) -> 1314816 (zeroed; lower filled)
  float*    Lw1    = (float*)(ws + 1314816);      // K*K (1 MB) -> 2363392 (copied from T in k_pre)
  int*      si     = (int*)(ws + 2363392);        // 16384 ints -> 2428928
  int*      sj     = (int*)(ws + 2428928);        // 16384 ints -> 2494464
  float*    sw     = (float*)(ws + 2494464);      // 16384 floats -> 2560000
  float*    PT     = (float*)(ws + 2560000);      // V*K floats (16 MB) -> 19337216

  hipMemsetAsync(ws, 0, 1314816, stream);         // cnt, tr, ld, htab, La

  k_pre<<<NB_TR + NB_CP + NB_ED, 256, 0, stream>>>(P, PT, X, ei, cnt, si, sj, sw, htab, T, Lw1);
  k_syrk<<<dim3(36, NZ_SYRK), 256, 0, stream>>>(cnt, si, sj, sw, PT, La, T, tr);

  k_fact0<<<2, 64, 0, stream>>>(La, Lw1, ld);
  for (int s = 0; s < 7; ++s) {
    int nt2 = 7 - s;
    k_cstep<<<dim3(nt2 * (nt2 + 1) / 2, 2), 256, 0, stream>>>(La, Lw1, ld, s);
  }
  k_combine<<<1, 1, 0, stream>>>(ld, tr, out);
}